// Round 13
// baseline (133.910 us; speedup 1.0000x reference)
//
#include <hip/hip_runtime.h>
#include <hip/hip_bf16.h>

typedef __bf16 bf16x8 __attribute__((ext_vector_type(8)));
typedef __bf16 bf16x4 __attribute__((ext_vector_type(4)));
typedef float  f32x4  __attribute__((ext_vector_type(4)));

#define B_  8
#define T_  2048
#define D_  1024
#define HS_ 64

// ---------------------------------------------------------------------------
// fp32 in/out; bf16 MFMA internally.
// pack_w -> qkv_fused (K-split M=32 + RING-3 CHUNKED x-staging fused into
//                      the kstep loop) -> attn_fused (R10, byte-identical).
//
// Round-23: R8/R9/R10/R12 ablation: qkv time invariant to occupancy (8 vs
// 16 waves/CU) and Wp traffic (196 vs 393 MB) -> bound by the SERIAL x-
// staging phase. Little's law: 8 waves x 32x16B outstanding / ~900cy HBM
// => ~2.8 TB/s ceiling => 67MB = ~24us ~= measured 25.5.
// Fix: stage x in 32x32 chunks (3-slot LDS ring/wave) interleaved with
// ksteps: loads for chunk c+2 issue before kstep c's MFMAs, write after.
// Staging overlaps compute; HBM spread over the kernel. Everything else
// (Wp ping-pong, acc, reduce, epilogues) byte-preserved from R10.
// ---------------------------------------------------------------------------

// Kernel 0: pack the three [D,HS] fp32 weights into bf16 MFMA-fragment order.
__global__ __launch_bounds__(256) void pack_w(
    const float* __restrict__ Wq, const float* __restrict__ Wk,
    const float* __restrict__ Wv, __bf16* __restrict__ Wp)
{
    const int t    = blockIdx.x * 256 + threadIdx.x;   // 0..24575
    const int lane = t & 63;
    const int pg   = t >> 6;                           // 0..383
    const int s    = pg & 3;
    const int c    = (pg >> 2) & 31;
    const int p    = pg >> 7;
    const int m16  = lane & 15;
    const int quad = lane >> 4;

    const float* W = (p == 0) ? Wq : (p == 1) ? Wk : Wv;
    const float* src = W + (size_t)(c * 32 + quad * 8) * 64 + s * 16 + m16;
    bf16x8 frag;
    #pragma unroll
    for (int j = 0; j < 8; ++j) frag[j] = (__bf16)src[(size_t)j * 64];
    *(bf16x8*)(Wp + (size_t)pg * 512 + lane * 8) = frag;
}

// Kernel 1: fused QKV projection, K-split M=32/wave, chunked x-staging.
// grid = 512 blocks (32 rows), block = 256 = 4 waves (wave owns K-window 256).
// Per wave: 8 ksteps; kstep c = {x-loads chunk c+2} {2 ds_read a-frags,
// 24 MFMA} {x-write chunk c+2, Wp WLOAD next}. 3-slot ring, rows padded
// to 40 elems (2-way banks, free).
__global__ __launch_bounds__(256) void qkv_fused(
    const float* __restrict__ x,     // [16384][1024] fp32
    const __bf16* __restrict__ Wp,   // [384][512] fragment-packed bf16
    const float* __restrict__ bq, const float* __restrict__ bk,
    const float* __restrict__ bv,
    __bf16* __restrict__ Q,          // [8][2048][64] row-major
    __bf16* __restrict__ Kp,         // [8][32][8][64][8] frag-packed
    __bf16* __restrict__ Vp)         // [8][32][8][64][8] frag-packed
{
    __shared__ alignas(16) unsigned char Smem[73728];  // Xc(30720) ∪ Red(73728)

    const int rt   = blockIdx.x;                  // 0..511
    const int wave = threadIdx.x >> 6;            // K-slice owner
    const int lane = threadIdx.x & 63;
    const int m16  = lane & 15;
    const int quad = lane >> 4;
    const int row0 = rt * 32;

    // per-wave 3-slot chunk ring: slot = [32 rows][40 elems] bf16 (2560B)
    __bf16* Xc = (__bf16*)(Smem + wave * 7680);
    const int srow = lane >> 3;                   // 0..7
    const int scol = (lane & 7) * 4;              // 0,4,..,28 (elem col)
    const float* xbase = x + (size_t)row0 * 1024 + wave * 256;

#define XLOAD(REGS, C)                                                     \
    {                                                                      \
        const float* xp_ = xbase + (C) * 32 + scol;                        \
        _Pragma("unroll")                                                  \
        for (int i_ = 0; i_ < 4; ++i_)                                     \
            REGS[i_] = *(const f32x4*)(xp_ + (size_t)(srow + 8 * i_) * 1024); \
    }
#define XWRITE(REGS, C)                                                    \
    {                                                                      \
        __bf16* xs_ = Xc + ((C) % 3) * 1280 + srow * 40 + scol;            \
        _Pragma("unroll")                                                  \
        for (int i_ = 0; i_ < 4; ++i_) {                                   \
            bf16x4 w_;                                                     \
            _Pragma("unroll")                                              \
            for (int e_ = 0; e_ < 4; ++e_) w_[e_] = (__bf16)REGS[i_][e_];  \
            *(bf16x4*)(xs_ + 8 * i_ * 40) = w_;                            \
        }                                                                  \
    }

    // ---- K-loop state ----
    f32x4 acc[3][4][2];
    #pragma unroll
    for (int p = 0; p < 3; ++p)
        #pragma unroll
        for (int s = 0; s < 4; ++s)
            #pragma unroll
            for (int t = 0; t < 2; ++t) acc[p][s][t] = {0.f, 0.f, 0.f, 0.f};

    bf16x8 bfA[12], bfB[12];
    f32x4 xr[4];

#define WLOAD(BUF, C)                                                      \
    {                                                                      \
        const int cb_ = wave * 8 + (C);                                    \
        _Pragma("unroll")                                                  \
        for (int ps_ = 0; ps_ < 12; ++ps_) {                               \
            const int p_ = ps_ >> 2, s_ = ps_ & 3;                         \
            BUF[ps_] = *(const bf16x8*)(Wp +                               \
                ((size_t)((p_ * 32 + cb_) * 4 + s_) << 9) + lane * 8);     \
        }                                                                  \
    }
#define KSTEP(BUF, C)                                                      \
    {                                                                      \
        bf16x8 a0 = *(const bf16x8*)&Xc[((C) % 3) * 1280 + m16 * 40 + quad * 8]; \
        bf16x8 a1 = *(const bf16x8*)&Xc[((C) % 3) * 1280 + (16 + m16) * 40 + quad * 8]; \
        __builtin_amdgcn_sched_barrier(0);                                 \
        _Pragma("unroll")                                                  \
        for (int ps_ = 0; ps_ < 12; ++ps_) {                               \
            acc[ps_ >> 2][ps_ & 3][0] =                                    \
                __builtin_amdgcn_mfma_f32_16x16x32_bf16(a0, BUF[ps_], acc[ps_ >> 2][ps_ & 3][0], 0, 0, 0); \
            acc[ps_ >> 2][ps_ & 3][1] =                                    \
                __builtin_amdgcn_mfma_f32_16x16x32_bf16(a1, BUF[ps_], acc[ps_ >> 2][ps_ & 3][1], 0, 0, 0); \
        }                                                                  \
    }

    // ---- prologue: chunks 0,1 staged; Wp batches 0,1 in flight ----
    XLOAD(xr, 0);  XWRITE(xr, 0);
    XLOAD(xr, 1);  XWRITE(xr, 1);
    WLOAD(bfA, 0);
    WLOAD(bfB, 1);
    __builtin_amdgcn_wave_barrier();   // pin DS write->read order (wave-local)

    // ---- 8 ksteps; stage chunk c+2 around kstep c ----
    XLOAD(xr, 2);
    KSTEP(bfA, 0);  XWRITE(xr, 2);  WLOAD(bfA, 2);
    XLOAD(xr, 3);
    KSTEP(bfB, 1);  XWRITE(xr, 3);  WLOAD(bfB, 3);
    XLOAD(xr, 4);
    KSTEP(bfA, 2);  XWRITE(xr, 4);  WLOAD(bfA, 4);
    XLOAD(xr, 5);
    KSTEP(bfB, 3);  XWRITE(xr, 5);  WLOAD(bfB, 5);
    XLOAD(xr, 6);
    KSTEP(bfA, 4);  XWRITE(xr, 6);  WLOAD(bfA, 6);
    XLOAD(xr, 7);
    KSTEP(bfB, 5);  XWRITE(xr, 7);  WLOAD(bfB, 7);
    KSTEP(bfA, 6);
    KSTEP(bfB, 7);
#undef KSTEP
#undef WLOAD
#undef XWRITE
#undef XLOAD

    // ---- cross-wave reduce (Red overlays dead Xc) + epilogue (R10) ----
    f32x4* Red = (f32x4*)Smem;                    // [3][24][64]
    __syncthreads();                              // all Xc reads done
    if (wave != 0) {
        #pragma unroll
        for (int p = 0; p < 3; ++p)
            #pragma unroll
            for (int s = 0; s < 4; ++s)
                #pragma unroll
                for (int t = 0; t < 2; ++t)
                    Red[((wave - 1) * 24 + (p * 4 + s) * 2 + t) * 64 + lane] = acc[p][s][t];
    }
    __syncthreads();
    if (wave != 0) return;

    #pragma unroll
    for (int p = 0; p < 3; ++p)
        #pragma unroll
        for (int s = 0; s < 4; ++s)
            #pragma unroll
            for (int t = 0; t < 2; ++t) {
                f32x4 sum = acc[p][s][t];
                #pragma unroll
                for (int w = 0; w < 3; ++w) {
                    f32x4 v = Red[(w * 24 + (p * 4 + s) * 2 + t) * 64 + lane];
                    #pragma unroll
                    for (int e = 0; e < 4; ++e) sum[e] += v[e];
                }
                acc[p][s][t] = sum;
            }

    #pragma unroll
    for (int t = 0; t < 2; ++t) {
        const int row0t = row0 + t * 16;

        // Q epilogue (p=0): row-major
        #pragma unroll
        for (int s = 0; s < 4; ++s) {
            const int h = s * 16 + m16;
            const float bia = bq[h];
            #pragma unroll
            for (int r = 0; r < 4; ++r)
                Q[(size_t)(row0t + quad * 4 + r) * 64 + h] = (__bf16)(acc[0][s][t][r] + bia);
        }

        const int tb = (row0t >> 4) & 3;              // 16-row quarter in tile
        const int jt = (row0t >> 6) & 31;             // key tile
        const int bb = row0t >> 11;                   // batch
        __bf16* kpt = Kp + (((size_t)bb * 32 + jt) * 8) * 512;
        __bf16* vpt = Vp + (((size_t)bb * 32 + jt) * 8) * 512;

        // K epilogue (p=1): scatter into frag-packed Kp
        {
            const int snb  = ((tb >> 1) << 1) | (quad & 1);
            const int m16b = ((tb & 1) << 3) | ((quad >> 1) << 2);  // + r
            #pragma unroll
            for (int s = 0; s < 4; ++s) {
                const int h = s * 16 + m16;
                const float bia = bk[h];
                const int g     = snb * 2 + (s >> 1);
                const int quadc = ((s & 1) << 1) | (m16 >> 3);
                const int j     = m16 & 7;
                #pragma unroll
                for (int r = 0; r < 4; ++r)
                    kpt[(size_t)g * 512 + (quadc * 16 + m16b + r) * 8 + j] =
                        (__bf16)(acc[1][s][t][r] + bia);
            }
        }
        // V epilogue (p=2): frag-packed Vp, r-contiguous -> bf16x4 stores
        {
            const int lanec = ((((tb & 1) << 1) | (quad >> 1)) << 4) + m16;
            const int jbase = (quad & 1) << 2;
            #pragma unroll
            for (int s = 0; s < 4; ++s) {
                const int h = s * 16 + m16;
                const float bia = bv[h];
                const int g = s * 2 + (tb >> 1);
                bf16x4 pack;
                #pragma unroll
                for (int r = 0; r < 4; ++r) pack[r] = (__bf16)(acc[2][s][t][r] + bia);
                *(bf16x4*)(vpt + (size_t)g * 512 + lanec * 8 + jbase) = pack;
            }
        }
    }
}

// Kernel 2: causal attention, fulltile scheme (byte-identical to R10).
// grid (32,8) x 512 thr (8 waves). Block s owns fulltiles fA=s, fB=63-s.
__global__ __launch_bounds__(512) void attn_fused(
    const __bf16* __restrict__ Q,    // [8][2048][64]
    const __bf16* __restrict__ Kp,   // [8][32][8][64][8]
    const __bf16* __restrict__ Vp,   // [8][32][8][64][8]
    float* __restrict__ O)           // [8][2048][64] fp32
{
    __shared__ float Mrg[8][64][37];  // o_A[16], mA, lA, o_B[16], mB, lB (+pad)

    const int s  = blockIdx.x;       // fulltile pair id 0..31
    const int b  = blockIdx.y;       // batch
    const int wave = threadIdx.x >> 6;   // 0..7 (split-K slice)
    const int lane = threadIdx.x & 63;
    const int m16  = lane & 15;
    const int quad = lane >> 4;
    const float SC = 0.18033688f;    // 0.125 * log2(e)

    const __bf16* Qb = Q  + (size_t)b * T_ * HS_;
    const __bf16* Kb = Kp + (size_t)b * 32 * 4096;
    const __bf16* Vb = Vp + (size_t)b * 32 * 4096;
    float* Obase     = O  + (size_t)b * T_ * HS_;

    bf16x8 vA[8];

#define LOADK(KA, JT)                                                      \
    {                                                                      \
        const __bf16* kb_ = Kb + (size_t)(JT) * 4096 + lane * 8;           \
        _Pragma("unroll")                                                  \
        for (int g_ = 0; g_ < 8; ++g_) KA[g_] = *(const bf16x8*)(kb_ + g_ * 512); \
    }
#define LOADV(JT)                                                          \
    {                                                                      \
        const __bf16* vb_ = Vb + (size_t)(JT) * 4096 + lane * 8;           \
        _Pragma("unroll")                                                  \
        for (int g_ = 0; g_ < 8; ++g_) vA[g_] = *(const bf16x8*)(vb_ + g_ * 512); \
    }

#define STEP(CK, NK)                                                       \
    {                                                                      \
        const int j0 = jt * 64;                                            \
        LOADV(jt);                      /* V current, used after softmax */ \
        f32x4 svA[4], svB[4];                                              \
        _Pragma("unroll")                                                  \
        for (int sn_ = 0; sn_ < 4; ++sn_) {                                \
            svA[sn_] = {0.f, 0.f, 0.f, 0.f};                               \
            svB[sn_] = {0.f, 0.f, 0.f, 0.f};                               \
            svA[sn_] = __builtin_amdgcn_mfma_f32_16x16x32_bf16(CK[sn_*2],   qA0, svA[sn_], 0, 0, 0); \
            svA[sn_] = __builtin_amdgcn_mfma_f32_16x16x32_bf16(CK[sn_*2+1], qA1, svA[sn_], 0, 0, 0); \
            svB[sn_] = __builtin_amdgcn_mfma_f32_16x16x32_bf16(CK[sn_*2],   qB0, svB[sn_], 0, 0, 0); \
            svB[sn_] = __builtin_amdgcn_mfma_f32_16x16x32_bf16(CK[sn_*2+1], qB1, svB[sn_], 0, 0, 0); \
        }                                                                  \
        if (jt + 8 < ntiles) LOADK(NK, jt + 8);                            \
        __builtin_amdgcn_sched_barrier(0);                                 \
        if (jt == ntiles - 1) {   /* diagonal tile: causal mask, per half */ \
            _Pragma("unroll")                                              \
            for (int sn_ = 0; sn_ < 4; ++sn_) {                            \
                const int kbase = j0 + ((sn_ >> 1) << 5) + (quad << 3) + ((sn_ & 1) << 2); \
                _Pragma("unroll")                                          \
                for (int r_ = 0; r_ < 4; ++r_) {                           \
                    svA[sn_][r_] = (kbase + r_ <= qrowA) ? svA[sn_][r_] : -3e38f; \
                    svB[sn_][r_] = (kbase + r_ <= qrowB) ? svB[sn_][r_] : -3e38f; \
                }                                                          \
            }                                                              \
        }                                                                  \
        float mxA = -3e38f, mxB = -3e38f;                                  \
        _Pragma("unroll")                                                  \
        for (int sn_ = 0; sn_ < 4; ++sn_)                                  \
            _Pragma("unroll")                                              \
            for (int r_ = 0; r_ < 4; ++r_) {                               \
                mxA = fmaxf(mxA, svA[sn_][r_]);                            \
                mxB = fmaxf(mxB, svB[sn_][r_]);                            \
            }                                                              \
        mxA = fmaxf(mxA, __shfl_xor(mxA, 16));                             \
        mxA = fmaxf(mxA, __shfl_xor(mxA, 32));                             \
        mxB = fmaxf(mxB, __shfl_xor(mxB, 16));                             \
        mxB = fmaxf(mxB, __shfl_xor(mxB, 32));                             \
        const float newmA = fmaxf(mA, mxA);                                \
        const float newmB = fmaxf(mB, mxB);                                \
        const float alA = exp2f((mA - newmA) * SC);                        \
        const float alB = exp2f((mB - newmB) * SC);                        \
        mA = newmA; mB = newmB;                                            \
        const float nmA = newmA * SC, nmB = newmB * SC;                    \
        float rsA = 0.f, rsB = 0.f;                                        \
        _Pragma("unroll")                                                  \
        for (int sn_ = 0; sn_ < 4; ++sn_)                                  \
            _Pragma("unroll")                                              \
            for (int r_ = 0; r_ < 4; ++r_) {                               \
                float pa_ = exp2f(__builtin_fmaf(svA[sn_][r_], SC, -nmA)); \
                float pb_ = exp2f(__builtin_fmaf(svB[sn_][r_], SC, -nmB)); \
                svA[sn_][r_] = pa_; rsA += pa_;                            \
                svB[sn_][r_] = pb_; rsB += pb_;                            \
            }                                                              \
        rsA += __shfl_xor(rsA, 16); rsA += __shfl_xor(rsA, 32);            \
        rsB += __shfl_xor(rsB, 16); rsB += __shfl_xor(rsB, 32);            \
        lA = lA * alA + rsA;  lB = lB * alB + rsB;                         \
        _Pragma("unroll")                                                  \
        for (int hs_ = 0; hs_ < 4; ++hs_)                                  \
            _Pragma("unroll")                                              \
            for (int r_ = 0; r_ < 4; ++r_) {                               \
                oA[hs_][r_] *= alA;                                        \
                oB[hs_][r_] *= alB;                                        \
            }                                                              \
        bf16x8 pA0, pA1, pB0, pB1;                                         \
        _Pragma("unroll")                                                  \
        for (int r_ = 0; r_ < 4; ++r_) {                                   \
            pA0[r_]     = (__bf16)svA[0][r_];                              \
            pA0[4 + r_] = (__bf16)svA[1][r_];                              \
            pA1[r_]     = (__bf16)svA[2][r_];                              \
            pA1[4 + r_] = (__bf16)svA[3][r_];                              \
            pB0[r_]     = (__bf16)svB[0][r_];                              \
            pB0[4 + r_] = (__bf16)svB[1][r_];                              \
            pB1[r_]     = (__bf16)svB[2][r_];                              \
            pB1[4 + r_] = (__bf16)svB[3][r_];                              \
        }                                                                  \
        _Pragma("unroll")                                                  \
        for (int hs_ = 0; hs_ < 4; ++hs_) {                                \
            oA[hs_] = __builtin_amdgcn_mfma_f32_16x16x32_bf16(vA[hs_*2],   pA0, oA[hs_], 0, 0, 0); \
            oA[hs_] = __builtin_amdgcn_mfma_f32_16x16x32_bf16(vA[hs_*2+1], pA1, oA[hs_], 0, 0, 0); \
            oB[hs_] = __builtin_amdgcn_mfma_f32_16x16x32_bf16(vA[hs_*2],   pB0, oB[hs_], 0, 0, 0); \
            oB[hs_] = __builtin_amdgcn_mfma_f32_16x16x32_bf16(vA[hs_*2+1], pB1, oB[hs_], 0, 0, 0); \
        }                                                                  \
    }

    auto runPhase = [&](const int f) {
        const int ntiles = (f >> 1) + 1;          // same for both halves
        const int qrowA  = f * 32 + m16;
        const int qrowB  = qrowA + 16;

        bf16x8 qA0 = *(const bf16x8*)(Qb + (size_t)qrowA * 64 + quad * 8);
        bf16x8 qA1 = *(const bf16x8*)(Qb + (size_t)qrowA * 64 + 32 + quad * 8);
        bf16x8 qB0 = *(const bf16x8*)(Qb + (size_t)qrowB * 64 + quad * 8);
        bf16x8 qB1 = *(const bf16x8*)(Qb + (size_t)qrowB * 64 + 32 + quad * 8);

        f32x4 oA[4], oB[4];
        #pragma unroll
        for (int hs = 0; hs < 4; ++hs) {
            oA[hs] = {0.f, 0.f, 0.f, 0.f};
            oB[hs] = {0.f, 0.f, 0.f, 0.f};
        }
        float mA = -3e38f, lA = 0.f, mB = -3e38f, lB = 0.f;

        bf16x8 kA[8], kB[8];
        int jt = wave;                     // 8-way split-K by tile parity
        if (jt < ntiles) {
            LOADK(kA, jt);
            while (true) {
                STEP(kA, kB);
                jt += 8; if (jt >= ntiles) break;
                STEP(kB, kA);
                jt += 8; if (jt >= ntiles) break;
            }
        }

        // 8-way split-K merge: everyone publishes, waves 0/1 combine A/B
        #pragma unroll
        for (int hs = 0; hs < 4; ++hs)
            #pragma unroll
            for (int r = 0; r < 4; ++r) {
                Mrg[wave][lane][hs * 4 + r]      = oA[hs][r];
                Mrg[wave][lane][18 + hs * 4 + r] = oB[hs][r];
            }
        Mrg[wave][lane][16] = mA; Mrg[wave][lane][17] = lA;
        Mrg[wave][lane][34] = mB; Mrg[wave][lane][35] = lB;
        __syncthreads();
        if (wave < 2) {
            const int off  = wave * 18;
            const int qrow = f * 32 + wave * 16 + m16;
            float mw[8], lw[8];
            #pragma unroll
            for (int w = 0; w < 8; ++w) {
                mw[w] = Mrg[w][lane][off + 16];
                lw[w] = Mrg[w][lane][off + 17];
            }
            float M = mw[0];
            #pragma unroll
            for (int w = 1; w < 8; ++w) M = fmaxf(M, mw[w]);
            float aw[8], den = 0.f;
            #pragma unroll
            for (int w = 0; w < 8; ++w) {
                aw[w] = exp2f((mw[w] - M) * SC);
                den += lw[w] * aw[w];
            }
            const float inv = 1.f / den;
            float* Ob = Obase + (size_t)qrow * 64;
            #pragma unroll
            for (int hs = 0; hs < 4; ++hs) {
                f32x4 v;
                #pragma unroll
                for (int r = 0; r < 4; ++r) {
                    float acc = 0.f;
                    #pragma unroll
                    for (int w = 0; w < 8; ++w)
                        acc += Mrg[w][lane][off + hs * 4 + r] * aw[w];
                    v[r] = acc * inv;
                }
                *(f32x4*)(Ob + hs * 16 + quad * 4) = v;
            }
        }
        __syncthreads();   // Mrg reusable for next phase
    };

    runPhase(s);           // (s>>1)+1 tiles
    runPhase(63 - s);      // 32-(s>>1) tiles  -> 33-34 uniform per block
#undef STEP
#undef LOADV
#undef LOADK
}

// ---------------------------------------------------------------------------
extern "C" void kernel_launch(void* const* d_in, const int* in_sizes, int n_in,
                              void* d_out, int out_size, void* d_ws, size_t ws_size,
                              hipStream_t stream)
{
    const float* x  = (const float*)d_in[0];
    const float* Wq = (const float*)d_in[1];
    const float* bq = (const float*)d_in[2];
    const float* Wk = (const float*)d_in[3];
    const float* bk = (const float*)d_in[4];
    const float* Wv = (const float*)d_in[5];
    const float* bv = (const float*)d_in[6];
    float* out = (float*)d_out;

    __bf16* Wp = (__bf16*)d_ws;              // 384*512 bf16         = 0.4 MB
    __bf16* Q  = Wp + 384 * 512;             // 8*2048*64 bf16       = 2 MB
    __bf16* Kp = Q  + (size_t)B_ * T_ * HS_; // frag-packed          = 2 MB
    __bf16* Vp = Kp + (size_t)B_ * T_ * HS_; // frag-packed          = 2 MB

    pack_w<<<96, 256, 0, stream>>>(Wq, Wk, Wv, Wp);
    qkv_fused<<<512, 256, 0, stream>>>(x, Wp, bq, bk, bv, Q, Kp, Vp);
    attn_fused<<<dim3(32, 8), 512, 0, stream>>>(Q, Kp, Vp, out);
}

// Round 14
// 132.735 us; speedup vs baseline: 1.0089x; 1.0089x over previous
//
#include <hip/hip_runtime.h>
#include <hip/hip_bf16.h>

typedef __bf16 bf16x8 __attribute__((ext_vector_type(8)));
typedef __bf16 bf16x4 __attribute__((ext_vector_type(4)));
typedef float  f32x4  __attribute__((ext_vector_type(4)));

#define B_  8
#define T_  2048
#define D_  1024
#define HS_ 64

// ---------------------------------------------------------------------------
// fp32 in/out; bf16 MFMA internally.
// pack_w -> qkv_fused (R10 exact: K-split M=32, bulk staging, Wp ping-pong)
//        -> attn_fused (HALFTILE blocks: 1024 blocks x 4 waves, 4-way
//                       split-K, LPT order, launch_bounds(256,3) -> 12
//                       waves/CU; merge/STEP formulas verbatim R8/R10).
//
// Round-24: qkv variants R8/R9/R10/R12/R13 all 25-31us -> R10 best, locked.
// attn at 8 waves/CU has MfmaUtil~28% (14.8us vs 4.1us MFMA floor); more
// waves/SIMD converts directly to util (m114 pipe overlap). Halftile
// decomposition gives 1024 blocks -> 3 resident/CU x 4 waves = 12 waves/CU
// + 4 backfill generations (LPT: h = 127-bx, heaviest first).
// ---------------------------------------------------------------------------

// Kernel 0: pack the three [D,HS] fp32 weights into bf16 MFMA-fragment order.
__global__ __launch_bounds__(256) void pack_w(
    const float* __restrict__ Wq, const float* __restrict__ Wk,
    const float* __restrict__ Wv, __bf16* __restrict__ Wp)
{
    const int t    = blockIdx.x * 256 + threadIdx.x;   // 0..24575
    const int lane = t & 63;
    const int pg   = t >> 6;                           // 0..383
    const int s    = pg & 3;
    const int c    = (pg >> 2) & 31;
    const int p    = pg >> 7;
    const int m16  = lane & 15;
    const int quad = lane >> 4;

    const float* W = (p == 0) ? Wq : (p == 1) ? Wk : Wv;
    const float* src = W + (size_t)(c * 32 + quad * 8) * 64 + s * 16 + m16;
    bf16x8 frag;
    #pragma unroll
    for (int j = 0; j < 8; ++j) frag[j] = (__bf16)src[(size_t)j * 64];
    *(bf16x8*)(Wp + (size_t)pg * 512 + lane * 8) = frag;
}

// Kernel 1: fused QKV projection (R10 exact), K-split M=32/wave,
// cross-kstep ping-pong prefetch of the 12 Wp fragments.
__global__ __launch_bounds__(256) void qkv_fused(
    const float* __restrict__ x,     // [16384][1024] fp32
    const __bf16* __restrict__ Wp,   // [384][512] fragment-packed bf16
    const float* __restrict__ bq, const float* __restrict__ bk,
    const float* __restrict__ bv,
    __bf16* __restrict__ Q,          // [8][2048][64] row-major
    __bf16* __restrict__ Kp,         // [8][32][8][64][8] frag-packed
    __bf16* __restrict__ Vp)         // [8][32][8][64][8] frag-packed
{
    __shared__ alignas(16) unsigned char Smem[73728];  // Xs(67584) ∪ Red(73728)

    const int rt   = blockIdx.x;                  // 0..511
    const int wave = threadIdx.x >> 6;            // K-slice owner
    const int lane = threadIdx.x & 63;
    const int m16  = lane & 15;
    const int quad = lane >> 4;
    const int row0 = rt * 32;

    __bf16* Xs = (__bf16*)(Smem + wave * 16896);  // 32 rows x 264 (pad 8)

    // ---- Phase 1: stage x-slice (32 rows x 256 cols), fp32 -> bf16 ----
    {
        const float* xsrc = x + (size_t)row0 * 1024 + wave * 256;
        const int sr = lane >> 5;                 // 0..1
        const int sc = (lane & 31) * 8;           // 0..248
        #pragma unroll
        for (int i = 0; i < 16; ++i) {
            const int r = i * 2 + sr;
            f32x4 v0 = *(const f32x4*)(xsrc + (size_t)r * 1024 + sc);
            f32x4 v1 = *(const f32x4*)(xsrc + (size_t)r * 1024 + sc + 4);
            bf16x8 w;
            #pragma unroll
            for (int e = 0; e < 4; ++e) { w[e] = (__bf16)v0[e]; w[4 + e] = (__bf16)v1[e]; }
            *(bf16x8*)&Xs[r * 264 + sc] = w;
        }
    }
    __builtin_amdgcn_wave_barrier();   // pin DS write->read order (wave-local)

    // ---- Phase 2: K-loop, ping-pong Wp prefetch, 2 row-halves ----
    f32x4 acc[3][4][2];
    #pragma unroll
    for (int p = 0; p < 3; ++p)
        #pragma unroll
        for (int s = 0; s < 4; ++s)
            #pragma unroll
            for (int t = 0; t < 2; ++t) acc[p][s][t] = {0.f, 0.f, 0.f, 0.f};

    bf16x8 bfA[12], bfB[12];

#define WLOAD(BUF, K0)                                                     \
    {                                                                      \
        const int cb_ = wave * 8 + ((K0) >> 5);                            \
        _Pragma("unroll")                                                  \
        for (int ps_ = 0; ps_ < 12; ++ps_) {                               \
            const int p_ = ps_ >> 2, s_ = ps_ & 3;                         \
            BUF[ps_] = *(const bf16x8*)(Wp +                               \
                ((size_t)((p_ * 32 + cb_) * 4 + s_) << 9) + lane * 8);     \
        }                                                                  \
    }
#define KSTEP(BUF, K0)                                                     \
    {                                                                      \
        bf16x8 a0 = *(const bf16x8*)&Xs[m16 * 264 + (K0) + quad * 8];      \
        bf16x8 a1 = *(const bf16x8*)&Xs[(16 + m16) * 264 + (K0) + quad * 8]; \
        __builtin_amdgcn_sched_barrier(0);                                 \
        _Pragma("unroll")                                                  \
        for (int ps_ = 0; ps_ < 12; ++ps_) {                               \
            acc[ps_ >> 2][ps_ & 3][0] =                                    \
                __builtin_amdgcn_mfma_f32_16x16x32_bf16(a0, BUF[ps_], acc[ps_ >> 2][ps_ & 3][0], 0, 0, 0); \
            acc[ps_ >> 2][ps_ & 3][1] =                                    \
                __builtin_amdgcn_mfma_f32_16x16x32_bf16(a1, BUF[ps_], acc[ps_ >> 2][ps_ & 3][1], 0, 0, 0); \
        }                                                                  \
    }

    WLOAD(bfA, 0);                       // prologue
    #pragma unroll
    for (int k0 = 0; k0 < 256; k0 += 64) {
        WLOAD(bfB, k0 + 32);             // prefetch next while computing cur
        KSTEP(bfA, k0);
        if (k0 + 64 < 256) WLOAD(bfA, k0 + 64);
        KSTEP(bfB, k0 + 32);
    }
#undef KSTEP
#undef WLOAD

    // ---- Phase 3: cross-wave reduce (Red overlays dead Xs) + epilogue ----
    f32x4* Red = (f32x4*)Smem;                    // [3][24][64]
    __syncthreads();                              // all Xs reads done
    if (wave != 0) {
        #pragma unroll
        for (int p = 0; p < 3; ++p)
            #pragma unroll
            for (int s = 0; s < 4; ++s)
                #pragma unroll
                for (int t = 0; t < 2; ++t)
                    Red[((wave - 1) * 24 + (p * 4 + s) * 2 + t) * 64 + lane] = acc[p][s][t];
    }
    __syncthreads();
    if (wave != 0) return;

    #pragma unroll
    for (int p = 0; p < 3; ++p)
        #pragma unroll
        for (int s = 0; s < 4; ++s)
            #pragma unroll
            for (int t = 0; t < 2; ++t) {
                f32x4 sum = acc[p][s][t];
                #pragma unroll
                for (int w = 0; w < 3; ++w) {
                    f32x4 v = Red[(w * 24 + (p * 4 + s) * 2 + t) * 64 + lane];
                    #pragma unroll
                    for (int e = 0; e < 4; ++e) sum[e] += v[e];
                }
                acc[p][s][t] = sum;
            }

    #pragma unroll
    for (int t = 0; t < 2; ++t) {
        const int row0t = row0 + t * 16;

        // Q epilogue (p=0): row-major
        #pragma unroll
        for (int s = 0; s < 4; ++s) {
            const int h = s * 16 + m16;
            const float bia = bq[h];
            #pragma unroll
            for (int r = 0; r < 4; ++r)
                Q[(size_t)(row0t + quad * 4 + r) * 64 + h] = (__bf16)(acc[0][s][t][r] + bia);
        }

        const int tb = (row0t >> 4) & 3;              // 16-row quarter in tile
        const int jt = (row0t >> 6) & 31;             // key tile
        const int bb = row0t >> 11;                   // batch
        __bf16* kpt = Kp + (((size_t)bb * 32 + jt) * 8) * 512;
        __bf16* vpt = Vp + (((size_t)bb * 32 + jt) * 8) * 512;

        // K epilogue (p=1): scatter into frag-packed Kp
        {
            const int snb  = ((tb >> 1) << 1) | (quad & 1);
            const int m16b = ((tb & 1) << 3) | ((quad >> 1) << 2);  // + r
            #pragma unroll
            for (int s = 0; s < 4; ++s) {
                const int h = s * 16 + m16;
                const float bia = bk[h];
                const int g     = snb * 2 + (s >> 1);
                const int quadc = ((s & 1) << 1) | (m16 >> 3);
                const int j     = m16 & 7;
                #pragma unroll
                for (int r = 0; r < 4; ++r)
                    kpt[(size_t)g * 512 + (quadc * 16 + m16b + r) * 8 + j] =
                        (__bf16)(acc[1][s][t][r] + bia);
            }
        }
        // V epilogue (p=2): frag-packed Vp, r-contiguous -> bf16x4 stores
        {
            const int lanec = ((((tb & 1) << 1) | (quad >> 1)) << 4) + m16;
            const int jbase = (quad & 1) << 2;
            #pragma unroll
            for (int s = 0; s < 4; ++s) {
                const int h = s * 16 + m16;
                const float bia = bv[h];
                const int g = s * 2 + (tb >> 1);
                bf16x4 pack;
                #pragma unroll
                for (int r = 0; r < 4; ++r) pack[r] = (__bf16)(acc[2][s][t][r] + bia);
                *(bf16x4*)(vpt + (size_t)g * 512 + lanec * 8 + jbase) = pack;
            }
        }
    }
}

// Kernel 2: causal attention, halftile blocks.
// grid (128,8) x 256 thr (4 waves). Block bx owns halftile h = 127-bx (LPT:
// heaviest first; backfill over ~4 generations balances causal skew).
// 4-way split-K by tile parity (jt=wave, +=4); per STEP: 16 frag loads
// (8K ping-pong + 8V at start) + 16 MFMA + lean exp2 softmax; diagonal-only
// mask. 4-way merge (R8-verified: waves 1-3 publish, wave 0 combines;
// empty waves publish m=-3e38,l=0 -> zero weight).
__global__ __launch_bounds__(256, 3) void attn_fused(
    const __bf16* __restrict__ Q,    // [8][2048][64]
    const __bf16* __restrict__ Kp,   // [8][32][8][64][8]
    const __bf16* __restrict__ Vp,   // [8][32][8][64][8]
    float* __restrict__ O)           // [8][2048][64] fp32
{
    __shared__ float Mrg[3][64][20];  // waves 1-3 partials: o[16], m, l

    const int h  = 127 - blockIdx.x; // halftile, longest-processing first
    const int b  = blockIdx.y;       // batch
    const int wave = threadIdx.x >> 6;   // 0..3 (split-K slice)
    const int lane = threadIdx.x & 63;
    const int m16  = lane & 15;
    const int quad = lane >> 4;
    const float SC = 0.18033688f;    // 0.125 * log2(e)

    const __bf16* Qb = Q  + (size_t)b * T_ * HS_;
    const __bf16* Kb = Kp + (size_t)b * 32 * 4096;
    const __bf16* Vb = Vp + (size_t)b * 32 * 4096;
    float* Obase     = O  + (size_t)b * T_ * HS_;

    const int ntiles = (h >> 2) + 1;
    const int qrow   = h * 16 + m16;

    bf16x8 qb0 = *(const bf16x8*)(Qb + (size_t)qrow * 64 + quad * 8);
    bf16x8 qb1 = *(const bf16x8*)(Qb + (size_t)qrow * 64 + 32 + quad * 8);

    f32x4 o[4];
    #pragma unroll
    for (int hs = 0; hs < 4; ++hs) o[hs] = {0.f, 0.f, 0.f, 0.f};
    float m_run = -3e38f, l_run = 0.f;

    bf16x8 kA[8], kB[8], vA[8];

#define LOADK(KA, JT)                                                      \
    {                                                                      \
        const __bf16* kb_ = Kb + (size_t)(JT) * 4096 + lane * 8;           \
        _Pragma("unroll")                                                  \
        for (int g_ = 0; g_ < 8; ++g_) KA[g_] = *(const bf16x8*)(kb_ + g_ * 512); \
    }
#define LOADV(JT)                                                          \
    {                                                                      \
        const __bf16* vb_ = Vb + (size_t)(JT) * 4096 + lane * 8;           \
        _Pragma("unroll")                                                  \
        for (int g_ = 0; g_ < 8; ++g_) vA[g_] = *(const bf16x8*)(vb_ + g_ * 512); \
    }

#define STEP(CK, NK)                                                       \
    {                                                                      \
        const int j0 = jt * 64;                                            \
        LOADV(jt);                      /* V current, used after softmax */ \
        f32x4 sv[4];                                                       \
        _Pragma("unroll")                                                  \
        for (int sn_ = 0; sn_ < 4; ++sn_) {                                \
            sv[sn_] = {0.f, 0.f, 0.f, 0.f};                                \
            sv[sn_] = __builtin_amdgcn_mfma_f32_16x16x32_bf16(CK[sn_*2],   qb0, sv[sn_], 0, 0, 0); \
            sv[sn_] = __builtin_amdgcn_mfma_f32_16x16x32_bf16(CK[sn_*2+1], qb1, sv[sn_], 0, 0, 0); \
        }                                                                  \
        if (jt + 4 < ntiles) LOADK(NK, jt + 4);                            \
        __builtin_amdgcn_sched_barrier(0);                                 \
        if (jt == ntiles - 1) {   /* diagonal tile: causal mask */         \
            _Pragma("unroll")                                              \
            for (int sn_ = 0; sn_ < 4; ++sn_) {                            \
                const int kbase = j0 + ((sn_ >> 1) << 5) + (quad << 3) + ((sn_ & 1) << 2); \
                _Pragma("unroll")                                          \
                for (int r_ = 0; r_ < 4; ++r_)                             \
                    sv[sn_][r_] = (kbase + r_ <= qrow) ? sv[sn_][r_] : -3e38f; \
            }                                                              \
        }                                                                  \
        float mx = -3e38f;                                                 \
        _Pragma("unroll")                                                  \
        for (int sn_ = 0; sn_ < 4; ++sn_)                                  \
            _Pragma("unroll")                                              \
            for (int r_ = 0; r_ < 4; ++r_) mx = fmaxf(mx, sv[sn_][r_]);    \
        mx = fmaxf(mx, __shfl_xor(mx, 16));                                \
        mx = fmaxf(mx, __shfl_xor(mx, 32));                                \
        const float newm  = fmaxf(m_run, mx);                              \
        const float alpha = exp2f((m_run - newm) * SC);                    \
        m_run = newm;                                                      \
        const float nm = newm * SC;                                        \
        float rs = 0.f;                                                    \
        _Pragma("unroll")                                                  \
        for (int sn_ = 0; sn_ < 4; ++sn_)                                  \
            _Pragma("unroll")                                              \
            for (int r_ = 0; r_ < 4; ++r_) {                               \
                float pv_ = exp2f(__builtin_fmaf(sv[sn_][r_], SC, -nm));   \
                sv[sn_][r_] = pv_;                                         \
                rs += pv_;                                                 \
            }                                                              \
        rs += __shfl_xor(rs, 16);                                          \
        rs += __shfl_xor(rs, 32);                                          \
        l_run = l_run * alpha + rs;                                        \
        _Pragma("unroll")                                                  \
        for (int hs_ = 0; hs_ < 4; ++hs_)                                  \
            _Pragma("unroll")                                              \
            for (int r_ = 0; r_ < 4; ++r_) o[hs_][r_] *= alpha;            \
        bf16x8 pb0, pb1;                                                   \
        _Pragma("unroll")                                                  \
        for (int r_ = 0; r_ < 4; ++r_) {                                   \
            pb0[r_]     = (__bf16)sv[0][r_];                               \
            pb0[4 + r_] = (__bf16)sv[1][r_];                               \
            pb1[r_]     = (__bf16)sv[2][r_];                               \
            pb1[4 + r_] = (__bf16)sv[3][r_];                               \
        }                                                                  \
        _Pragma("unroll")                                                  \
        for (int hs_ = 0; hs_ < 4; ++hs_) {                                \
            o[hs_] = __builtin_amdgcn_mfma_f32_16x16x32_bf16(vA[hs_*2],   pb0, o[hs_], 0, 0, 0); \
            o[hs_] = __builtin_amdgcn_mfma_f32_16x16x32_bf16(vA[hs_*2+1], pb1, o[hs_], 0, 0, 0); \
        }                                                                  \
    }

    int jt = wave;                     // 4-way split-K by tile parity
    if (jt < ntiles) {
        LOADK(kA, jt);
        while (true) {
            STEP(kA, kB);
            jt += 4; if (jt >= ntiles) break;
            STEP(kB, kA);
            jt += 4; if (jt >= ntiles) break;
        }
    }
#undef STEP
#undef LOADV
#undef LOADK

    // block-local 4-way split-K merge (waves 1-3 publish, wave0 writes)
    if (wave != 0) {
        #pragma unroll
        for (int hs = 0; hs < 4; ++hs)
            #pragma unroll
            for (int r = 0; r < 4; ++r) Mrg[wave - 1][lane][hs * 4 + r] = o[hs][r];
        Mrg[wave - 1][lane][16] = m_run;
        Mrg[wave - 1][lane][17] = l_run;
    }
    __syncthreads();
    if (wave == 0) {
        float mw[3], lw[3];
        #pragma unroll
        for (int w = 0; w < 3; ++w) {
            mw[w] = Mrg[w][lane][16];
            lw[w] = Mrg[w][lane][17];
        }
        float M = fmaxf(fmaxf(m_run, mw[0]), fmaxf(mw[1], mw[2]));
        const float a0 = exp2f((m_run - M) * SC);
        float aw[3];
        float den = l_run * a0;
        #pragma unroll
        for (int w = 0; w < 3; ++w) {
            aw[w] = exp2f((mw[w] - M) * SC);
            den += lw[w] * aw[w];
        }
        const float inv = 1.f / den;
        float* Ob = Obase + (size_t)qrow * 64;
        #pragma unroll
        for (int hs = 0; hs < 4; ++hs) {
            f32x4 v;
            #pragma unroll
            for (int r = 0; r < 4; ++r) {
                float acc = o[hs][r] * a0;
                #pragma unroll
                for (int w = 0; w < 3; ++w)
                    acc += Mrg[w][lane][hs * 4 + r] * aw[w];
                v[r] = acc * inv;
            }
            *(f32x4*)(Ob + hs * 16 + quad * 4) = v;
        }
    }
}

// ---------------------------------------------------------------------------
extern "C" void kernel_launch(void* const* d_in, const int* in_sizes, int n_in,
                              void* d_out, int out_size, void* d_ws, size_t ws_size,
                              hipStream_t stream)
{
    const float* x  = (const float*)d_in[0];
    const float* Wq = (const float*)d_in[1];
    const float* bq = (const float*)d_in[2];
    const float* Wk = (const float*)d_in[3];
    const float* bk = (const float*)d_in[4];
    const float* Wv = (const float*)d_in[5];
    const float* bv = (const float*)d_in[6];
    float* out = (float*)d_out;

    __bf16* Wp = (__bf16*)d_ws;              // 384*512 bf16         = 0.4 MB
    __bf16* Q  = Wp + 384 * 512;             // 8*2048*64 bf16       = 2 MB
    __bf16* Kp = Q  + (size_t)B_ * T_ * HS_; // frag-packed          = 2 MB
    __bf16* Vp = Kp + (size_t)B_ * T_ * HS_; // frag-packed          = 2 MB

    pack_w<<<96, 256, 0, stream>>>(Wq, Wk, Wv, Wp);
    qkv_fused<<<512, 256, 0, stream>>>(x, Wp, bq, bk, bv, Q, Kp, Vp);
    attn_fused<<<dim3(128, 8), 256, 0, stream>>>(Q, Kp, Vp, out);
}